// Round 1
// baseline (127.192 us; speedup 1.0000x reference)
//
#include <hip/hip_runtime.h>
#include <math.h>

#define QN 4096
#define NN 1024
#define FD 64
#define HD 128

// workspace layout (float offsets)
#define OFF_B     0                      // [1024][128]
#define OFF_U     131072                 // [4096][128]
#define OFF_L     655360                 // [1024 n][4096 q] logits
#define OFF_PM    4849664                // [4 c][4096 q] partial max
#define OFF_PART  4866048                // [8*64][4096]  partial agg (c,f,q)
#define OFF_SPART 6963200                // [8][4096]     partial sum
// end: 6995968 floats = ~28 MB

// ---------------- K1: B[n,h], U[q,h] precompute ----------------
__global__ __launch_bounds__(256) void k1_prep(
    const float* __restrict__ qp, const float* __restrict__ nf,
    const float* __restrict__ npos, const float* __restrict__ aW1,
    const float* __restrict__ ab1, float* __restrict__ B, float* __restrict__ U) {
  int idx = blockIdx.x * 256 + threadIdx.x;
  if (idx < QN * HD) {
    int q = idx >> 7, h = idx & 127;
    U[idx] = qp[q*3+0] * aW1[(FD+0)*HD + h]
           + qp[q*3+1] * aW1[(FD+1)*HD + h]
           + qp[q*3+2] * aW1[(FD+2)*HD + h];
  } else {
    int i2 = idx - QN * HD;
    if (i2 < NN * HD) {
      int n = i2 >> 7, h = i2 & 127;
      float s = ab1[h];
      #pragma unroll
      for (int f = 0; f < FD; ++f) s = fmaf(nf[n*FD+f], aW1[f*HD+h], s);
      s -= npos[n*3+0] * aW1[(FD+0)*HD + h]
         + npos[n*3+1] * aW1[(FD+1)*HD + h]
         + npos[n*3+2] * aW1[(FD+2)*HD + h];
      B[i2] = s;
    }
  }
}

// ---------------- K2: logits L[n][q] = (sum_h relu(B+U)*v + ab2) * w ----------------
__global__ __launch_bounds__(256) void k2_logits(
    const float* __restrict__ Bg, const float* __restrict__ Ug,
    const float* __restrict__ aW2, const float* __restrict__ ab2,
    const float* __restrict__ qp, const float* __restrict__ npos,
    float* __restrict__ L) {
  __shared__ float Bs[64 * HD];   // 32 KB
  const int q0 = blockIdx.x * 64, n0 = blockIdx.y * 64;
  const int t = threadIdx.x;
  {
    const float4* src = (const float4*)(Bg + n0 * HD);
    float4* dst = (float4*)Bs;
    #pragma unroll
    for (int r = 0; r < 8; ++r) dst[r*256 + t] = src[r*256 + t];
  }
  __syncthreads();
  const int lane = t & 63, wid = t >> 6;
  const int q = q0 + lane;
  const int nb = wid * 16;

  float acc[16];
  #pragma unroll
  for (int i = 0; i < 16; ++i) acc[i] = 0.f;

  const float4* Uq = (const float4*)(Ug + q * HD);

  for (int hc = 0; hc < 16; ++hc) {   // 8 h per chunk
    float4 u0 = Uq[hc*2 + 0];
    float4 u1 = Uq[hc*2 + 1];
    float4 v0 = *(const float4*)(aW2 + hc*8 + 0);
    float4 v1 = *(const float4*)(aW2 + hc*8 + 4);
    #pragma unroll
    for (int n = 0; n < 16; ++n) {
      const float4* bp = (const float4*)(Bs + (nb + n) * HD + hc*8);
      float4 b0 = bp[0], b1 = bp[1];
      float r;
      r = fmaxf(b0.x + u0.x, 0.f); acc[n] = fmaf(r, v0.x, acc[n]);
      r = fmaxf(b0.y + u0.y, 0.f); acc[n] = fmaf(r, v0.y, acc[n]);
      r = fmaxf(b0.z + u0.z, 0.f); acc[n] = fmaf(r, v0.z, acc[n]);
      r = fmaxf(b0.w + u0.w, 0.f); acc[n] = fmaf(r, v0.w, acc[n]);
      r = fmaxf(b1.x + u1.x, 0.f); acc[n] = fmaf(r, v1.x, acc[n]);
      r = fmaxf(b1.y + u1.y, 0.f); acc[n] = fmaf(r, v1.y, acc[n]);
      r = fmaxf(b1.z + u1.z, 0.f); acc[n] = fmaf(r, v1.z, acc[n]);
      r = fmaxf(b1.w + u1.w, 0.f); acc[n] = fmaf(r, v1.w, acc[n]);
    }
  }

  const float qx = qp[q*3+0], qy = qp[q*3+1];
  const float bias2 = ab2[0];
  #pragma unroll
  for (int n = 0; n < 16; ++n) {
    int nn = n0 + nb + n;
    float px = npos[nn*3+0], py = npos[nn*3+1];
    float dx = qx - px, dy = qy - py;
    float w = 1.f / (sqrtf(dx*dx + dy*dy) + 1e-6f);
    L[nn * QN + q] = (acc[n] + bias2) * w;
  }
}

// ---------------- K3: partial max over n ----------------
__global__ __launch_bounds__(256) void k3_max(const float* __restrict__ L,
                                              float* __restrict__ pm) {
  __shared__ float red[4][64];
  int b = blockIdx.x;
  int qt = b & 63, c = b >> 6;          // c in [0,4)
  int t = threadIdx.x, lane = t & 63, w = t >> 6;
  int q = qt * 64 + lane;
  int nbase = c * 256 + w * 64;
  float m = -3.4e38f;
  for (int i = 0; i < 64; ++i) m = fmaxf(m, L[(nbase + i) * QN + q]);
  red[w][lane] = m;
  __syncthreads();
  if (t < 64) {
    float mm = fmaxf(fmaxf(red[0][t], red[1][t]), fmaxf(red[2][t], red[3][t]));
    pm[c * QN + qt * 64 + t] = mm;
  }
}

// ---------------- K4: exp + partial aggregate ----------------
__global__ __launch_bounds__(256) void k4_agg(
    const float* __restrict__ L, const float* __restrict__ pm,
    const float* __restrict__ nf, float* __restrict__ part,
    float* __restrict__ spart) {
  __shared__ float red[4][32][64];   // 32 KB
  __shared__ float sred[4][64];
  int b = blockIdx.x;
  int qt = b & 63, c = b >> 6;        // c in [0,8)
  int t = threadIdx.x, lane = t & 63, w = t >> 6;
  int q = qt * 64 + lane;
  float m = fmaxf(fmaxf(pm[q], pm[QN + q]), fmaxf(pm[2*QN + q], pm[3*QN + q]));

  float acc[64];
  #pragma unroll
  for (int f = 0; f < 64; ++f) acc[f] = 0.f;
  float s = 0.f;

  int nbase = c * 128 + w * 32;
  for (int i = 0; i < 32; ++i) {
    int n = nbase + i;
    float p = exp2f((L[n * QN + q] - m) * 1.44269504088896f);
    s += p;
    const float4* nfr = (const float4*)(nf + n * FD);
    #pragma unroll
    for (int g = 0; g < 4; ++g) {
      float4 a0 = nfr[g*4+0], a1 = nfr[g*4+1], a2 = nfr[g*4+2], a3 = nfr[g*4+3];
      acc[g*16+ 0] = fmaf(p, a0.x, acc[g*16+ 0]);
      acc[g*16+ 1] = fmaf(p, a0.y, acc[g*16+ 1]);
      acc[g*16+ 2] = fmaf(p, a0.z, acc[g*16+ 2]);
      acc[g*16+ 3] = fmaf(p, a0.w, acc[g*16+ 3]);
      acc[g*16+ 4] = fmaf(p, a1.x, acc[g*16+ 4]);
      acc[g*16+ 5] = fmaf(p, a1.y, acc[g*16+ 5]);
      acc[g*16+ 6] = fmaf(p, a1.z, acc[g*16+ 6]);
      acc[g*16+ 7] = fmaf(p, a1.w, acc[g*16+ 7]);
      acc[g*16+ 8] = fmaf(p, a2.x, acc[g*16+ 8]);
      acc[g*16+ 9] = fmaf(p, a2.y, acc[g*16+ 9]);
      acc[g*16+10] = fmaf(p, a2.z, acc[g*16+10]);
      acc[g*16+11] = fmaf(p, a2.w, acc[g*16+11]);
      acc[g*16+12] = fmaf(p, a3.x, acc[g*16+12]);
      acc[g*16+13] = fmaf(p, a3.y, acc[g*16+13]);
      acc[g*16+14] = fmaf(p, a3.z, acc[g*16+14]);
      acc[g*16+15] = fmaf(p, a3.w, acc[g*16+15]);
    }
  }

  sred[w][lane] = s;
  // pass 0: f in [0,32)
  #pragma unroll
  for (int f = 0; f < 32; ++f) red[w][f][lane] = acc[f];
  __syncthreads();
  for (int idx = t; idx < 2048; idx += 256) {
    int f = idx >> 6, qq = idx & 63;
    float sum = red[0][f][qq] + red[1][f][qq] + red[2][f][qq] + red[3][f][qq];
    part[(c*64 + f) * QN + qt*64 + qq] = sum;
  }
  __syncthreads();
  // pass 1: f in [32,64)
  #pragma unroll
  for (int f = 0; f < 32; ++f) red[w][f][lane] = acc[32 + f];
  __syncthreads();
  for (int idx = t; idx < 2048; idx += 256) {
    int f = idx >> 6, qq = idx & 63;
    float sum = red[0][f][qq] + red[1][f][qq] + red[2][f][qq] + red[3][f][qq];
    part[(c*64 + 32 + f) * QN + qt*64 + qq] = sum;
  }
  __syncthreads();
  if (t < 64) {
    spart[c * QN + qt*64 + t] = sred[0][t] + sred[1][t] + sred[2][t] + sred[3][t];
  }
}

// ---------------- K5: reduce partials, normalize, decode ----------------
__global__ __launch_bounds__(256) void k5_dec(
    const float* __restrict__ part, const float* __restrict__ spart,
    const float* __restrict__ dW1, const float* __restrict__ db1,
    const float* __restrict__ dW2, const float* __restrict__ db2,
    float* __restrict__ out) {
  __shared__ float aggL[2][64];
  __shared__ float h1s[2][128];
  int t = threadIdx.x;
  int qb = blockIdx.x * 2;
  if (t < 128) {
    int q2 = t >> 6, f = t & 63;
    int q = qb + q2;
    float v = 0.f;
    #pragma unroll
    for (int c = 0; c < 8; ++c) v += part[(c*64 + f) * QN + q];
    float s = 0.f;
    #pragma unroll
    for (int c = 0; c < 8; ++c) s += spart[c * QN + q];
    aggL[q2][f] = v / s;
  }
  __syncthreads();
  {
    int q2 = t >> 7, h = t & 127;
    float a = db1[h];
    #pragma unroll
    for (int f = 0; f < 64; ++f) a = fmaf(aggL[q2][f], dW1[f*HD + h], a);
    h1s[q2][h] = fmaxf(a, 0.f);
  }
  __syncthreads();
  if (t < 6) {
    int q2 = t / 3, o = t % 3;
    float a = db2[o];
    #pragma unroll
    for (int h = 0; h < 128; ++h) a = fmaf(h1s[q2][h], dW2[h*3 + o], a);
    out[(qb + q2) * 3 + o] = a;
  }
}

extern "C" void kernel_launch(void* const* d_in, const int* in_sizes, int n_in,
                              void* d_out, int out_size, void* d_ws, size_t ws_size,
                              hipStream_t stream) {
  const float* qp   = (const float*)d_in[0];
  const float* nf   = (const float*)d_in[1];
  const float* npos = (const float*)d_in[2];
  const float* aW1  = (const float*)d_in[3];
  const float* ab1  = (const float*)d_in[4];
  const float* aW2  = (const float*)d_in[5];
  const float* ab2  = (const float*)d_in[6];
  const float* dW1  = (const float*)d_in[7];
  const float* db1  = (const float*)d_in[8];
  const float* dW2  = (const float*)d_in[9];
  const float* db2  = (const float*)d_in[10];

  float* ws    = (float*)d_ws;
  float* B     = ws + OFF_B;
  float* U     = ws + OFF_U;
  float* L     = ws + OFF_L;
  float* pm    = ws + OFF_PM;
  float* part  = ws + OFF_PART;
  float* spart = ws + OFF_SPART;

  hipLaunchKernelGGL(k1_prep, dim3(2560), dim3(256), 0, stream,
                     qp, nf, npos, aW1, ab1, B, U);
  hipLaunchKernelGGL(k2_logits, dim3(64, 16), dim3(256), 0, stream,
                     B, U, aW2, ab2, qp, npos, L);
  hipLaunchKernelGGL(k3_max, dim3(256), dim3(256), 0, stream, L, pm);
  hipLaunchKernelGGL(k4_agg, dim3(512), dim3(256), 0, stream, L, pm, nf, part, spart);
  hipLaunchKernelGGL(k5_dec, dim3(2048), dim3(256), 0, stream,
                     part, spart, dW1, db1, dW2, db2, (float*)d_out);
}

// Round 2
// 121.893 us; speedup vs baseline: 1.0435x; 1.0435x over previous
//
#include <hip/hip_runtime.h>
#include <math.h>

#define QN 4096
#define NN 1024
#define FD 64
#define HD 128

// workspace layout (float offsets)
#define OFF_UT    0                      // U_T [128 h][4096 q]
#define OFF_B     524288                 // B   [1024 n][128 h]
#define OFF_L     655360                 // L   [1024 n][4096 q]
#define OFF_PM    4849664                // pm  [4096 q][32 ntile]
#define OFF_PART  4980736                // part[8c*64f][4096 q]
#define OFF_SPART 7077888                // spart[8c][4096 q]
// end: 7110656 floats ~= 28.4 MB

// ---------------- K1: B[n,h], U_T[h,q] precompute ----------------
__global__ __launch_bounds__(256) void k1_prep(
    const float* __restrict__ qp, const float* __restrict__ nf,
    const float* __restrict__ npos, const float* __restrict__ aW1,
    const float* __restrict__ ab1, float* __restrict__ B, float* __restrict__ UT) {
  int idx = blockIdx.x * 256 + threadIdx.x;
  if (idx < QN * HD) {
    int h = idx >> 12, q = idx & 4095;      // U_T[h][q]
    UT[idx] = qp[q*3+0] * aW1[(FD+0)*HD + h]
            + qp[q*3+1] * aW1[(FD+1)*HD + h]
            + qp[q*3+2] * aW1[(FD+2)*HD + h];
  } else {
    int i2 = idx - QN * HD;
    if (i2 < NN * HD) {
      int n = i2 >> 7, h = i2 & 127;
      float s = ab1[h];
      #pragma unroll
      for (int f = 0; f < FD; ++f) s = fmaf(nf[n*FD+f], aW1[f*HD+h], s);
      s -= npos[n*3+0] * aW1[(FD+0)*HD + h]
         + npos[n*3+1] * aW1[(FD+1)*HD + h]
         + npos[n*3+2] * aW1[(FD+2)*HD + h];
      B[i2] = s;
    }
  }
}

// ---------------- K2: logits L[n][q] + per-tile max pm[q][ny] ----------------
// tile: 256 q x 32 n per block; 4 q per lane; wave w owns n-slice [w*8, w*8+8)
__global__ __launch_bounds__(256) void k2_logits(
    const float* __restrict__ Bg, const float* __restrict__ UT,
    const float* __restrict__ aW2, const float* __restrict__ ab2,
    const float* __restrict__ qp, const float* __restrict__ npos,
    float* __restrict__ L, float* __restrict__ pm) {
  __shared__ float Bs[32 * HD];      // 16 KB
  __shared__ float red[4][4][64];    // 4 KB
  const int q0 = blockIdx.x * 256, n0 = blockIdx.y * 32;
  const int t = threadIdx.x;
  {
    const float4* src = (const float4*)(Bg + n0 * HD);
    float4* dst = (float4*)Bs;
    #pragma unroll
    for (int r = 0; r < 4; ++r) dst[r*256 + t] = src[r*256 + t];
  }
  __syncthreads();
  const int lane = t & 63, w = t >> 6;
  const int nb = w * 8;

  float acc[4][8];
  #pragma unroll
  for (int qq = 0; qq < 4; ++qq)
    #pragma unroll
    for (int nn = 0; nn < 8; ++nn) acc[qq][nn] = 0.f;

  for (int hc = 0; hc < 16; ++hc) {
    // U: coalesced dword loads from transposed layout (lane-consecutive q)
    float u[4][8];
    #pragma unroll
    for (int hh = 0; hh < 8; ++hh) {
      const float* up = UT + (hc*8 + hh) * QN + q0 + lane;
      #pragma unroll
      for (int qq = 0; qq < 4; ++qq) u[qq][hh] = up[qq*64];
    }
    float v[8];
    #pragma unroll
    for (int hh = 0; hh < 8; ++hh) v[hh] = aW2[hc*8 + hh];

    #pragma unroll
    for (int nn = 0; nn < 8; ++nn) {
      const float4* bp = (const float4*)(Bs + (nb + nn) * HD + hc*8);
      float4 b0 = bp[0], b1 = bp[1];
      float bb[8] = {b0.x, b0.y, b0.z, b0.w, b1.x, b1.y, b1.z, b1.w};
      #pragma unroll
      for (int qq = 0; qq < 4; ++qq) {
        #pragma unroll
        for (int hh = 0; hh < 8; ++hh) {
          float r = fmaxf(bb[hh] + u[qq][hh], 0.f);
          acc[qq][nn] = fmaf(r, v[hh], acc[qq][nn]);
        }
      }
    }
  }

  const float bias2 = ab2[0];
  float qx[4], qy[4], m4[4];
  #pragma unroll
  for (int qq = 0; qq < 4; ++qq) {
    int q = q0 + qq*64 + lane;
    qx[qq] = qp[q*3+0];
    qy[qq] = qp[q*3+1];
    m4[qq] = -3.4e38f;
  }
  #pragma unroll
  for (int nn = 0; nn < 8; ++nn) {
    int n = n0 + nb + nn;
    float px = npos[n*3+0], py = npos[n*3+1];
    #pragma unroll
    for (int qq = 0; qq < 4; ++qq) {
      float dx = qx[qq] - px, dy = qy[qq] - py;
      float wgt = 1.f / (sqrtf(dx*dx + dy*dy) + 1e-6f);
      float lg = (acc[qq][nn] + bias2) * wgt;
      L[n * QN + q0 + qq*64 + lane] = lg;
      m4[qq] = fmaxf(m4[qq], lg);
    }
  }
  #pragma unroll
  for (int qq = 0; qq < 4; ++qq) red[w][qq][lane] = m4[qq];
  __syncthreads();
  {
    int qq = t >> 6, ll = t & 63;
    float mm = fmaxf(fmaxf(red[0][qq][ll], red[1][qq][ll]),
                     fmaxf(red[2][qq][ll], red[3][qq][ll]));
    pm[(q0 + qq*64 + ll) * 32 + blockIdx.y] = mm;
  }
}

// ---------------- K4: exp + partial aggregate ----------------
__global__ __launch_bounds__(256) void k4_agg(
    const float* __restrict__ L, const float* __restrict__ pm,
    const float* __restrict__ nf, float* __restrict__ part,
    float* __restrict__ spart) {
  __shared__ float red[4][32][64];   // 32 KB
  __shared__ float sred[4][64];
  int b = blockIdx.x;
  int qt = b & 63, c = b >> 6;        // c in [0,8)
  int t = threadIdx.x, lane = t & 63, w = t >> 6;
  int q = qt * 64 + lane;

  float m = -3.4e38f;
  {
    const float4* pmq = (const float4*)(pm + q * 32);
    #pragma unroll
    for (int g = 0; g < 8; ++g) {
      float4 pv = pmq[g];
      m = fmaxf(m, fmaxf(fmaxf(pv.x, pv.y), fmaxf(pv.z, pv.w)));
    }
  }

  float acc[64];
  #pragma unroll
  for (int f = 0; f < 64; ++f) acc[f] = 0.f;
  float s = 0.f;

  int nbase = c * 128 + w * 32;
  for (int i = 0; i < 32; ++i) {
    int n = nbase + i;
    float p = exp2f((L[n * QN + q] - m) * 1.44269504088896f);
    s += p;
    const float4* nfr = (const float4*)(nf + n * FD);
    #pragma unroll
    for (int g = 0; g < 4; ++g) {
      float4 a0 = nfr[g*4+0], a1 = nfr[g*4+1], a2 = nfr[g*4+2], a3 = nfr[g*4+3];
      acc[g*16+ 0] = fmaf(p, a0.x, acc[g*16+ 0]);
      acc[g*16+ 1] = fmaf(p, a0.y, acc[g*16+ 1]);
      acc[g*16+ 2] = fmaf(p, a0.z, acc[g*16+ 2]);
      acc[g*16+ 3] = fmaf(p, a0.w, acc[g*16+ 3]);
      acc[g*16+ 4] = fmaf(p, a1.x, acc[g*16+ 4]);
      acc[g*16+ 5] = fmaf(p, a1.y, acc[g*16+ 5]);
      acc[g*16+ 6] = fmaf(p, a1.z, acc[g*16+ 6]);
      acc[g*16+ 7] = fmaf(p, a1.w, acc[g*16+ 7]);
      acc[g*16+ 8] = fmaf(p, a2.x, acc[g*16+ 8]);
      acc[g*16+ 9] = fmaf(p, a2.y, acc[g*16+ 9]);
      acc[g*16+10] = fmaf(p, a2.z, acc[g*16+10]);
      acc[g*16+11] = fmaf(p, a2.w, acc[g*16+11]);
      acc[g*16+12] = fmaf(p, a3.x, acc[g*16+12]);
      acc[g*16+13] = fmaf(p, a3.y, acc[g*16+13]);
      acc[g*16+14] = fmaf(p, a3.z, acc[g*16+14]);
      acc[g*16+15] = fmaf(p, a3.w, acc[g*16+15]);
    }
  }

  sred[w][lane] = s;
  #pragma unroll
  for (int f = 0; f < 32; ++f) red[w][f][lane] = acc[f];
  __syncthreads();
  for (int idx = t; idx < 2048; idx += 256) {
    int f = idx >> 6, qq = idx & 63;
    float sum = red[0][f][qq] + red[1][f][qq] + red[2][f][qq] + red[3][f][qq];
    part[(c*64 + f) * QN + qt*64 + qq] = sum;
  }
  __syncthreads();
  #pragma unroll
  for (int f = 0; f < 32; ++f) red[w][f][lane] = acc[32 + f];
  __syncthreads();
  for (int idx = t; idx < 2048; idx += 256) {
    int f = idx >> 6, qq = idx & 63;
    float sum = red[0][f][qq] + red[1][f][qq] + red[2][f][qq] + red[3][f][qq];
    part[(c*64 + 32 + f) * QN + qt*64 + qq] = sum;
  }
  __syncthreads();
  if (t < 64) {
    spart[c * QN + qt*64 + t] = sred[0][t] + sred[1][t] + sred[2][t] + sred[3][t];
  }
}

// ---------------- K5: reduce partials, normalize, decode ----------------
__global__ __launch_bounds__(256) void k5_dec(
    const float* __restrict__ part, const float* __restrict__ spart,
    const float* __restrict__ dW1, const float* __restrict__ db1,
    const float* __restrict__ dW2, const float* __restrict__ db2,
    float* __restrict__ out) {
  __shared__ float aggL[2][64];
  __shared__ float h1s[2][128];
  int t = threadIdx.x;
  int qb = blockIdx.x * 2;
  if (t < 128) {
    int q2 = t >> 6, f = t & 63;
    int q = qb + q2;
    float v = 0.f;
    #pragma unroll
    for (int c = 0; c < 8; ++c) v += part[(c*64 + f) * QN + q];
    float s = 0.f;
    #pragma unroll
    for (int c = 0; c < 8; ++c) s += spart[c * QN + q];
    aggL[q2][f] = v / s;
  }
  __syncthreads();
  {
    int q2 = t >> 7, h = t & 127;
    float a = db1[h];
    #pragma unroll
    for (int f = 0; f < 64; ++f) a = fmaf(aggL[q2][f], dW1[f*HD + h], a);
    h1s[q2][h] = fmaxf(a, 0.f);
  }
  __syncthreads();
  if (t < 6) {
    int q2 = t / 3, o = t % 3;
    float a = db2[o];
    #pragma unroll
    for (int h = 0; h < 128; ++h) a = fmaf(h1s[q2][h], dW2[h*3 + o], a);
    out[(qb + q2) * 3 + o] = a;
  }
}

extern "C" void kernel_launch(void* const* d_in, const int* in_sizes, int n_in,
                              void* d_out, int out_size, void* d_ws, size_t ws_size,
                              hipStream_t stream) {
  const float* qp   = (const float*)d_in[0];
  const float* nf   = (const float*)d_in[1];
  const float* npos = (const float*)d_in[2];
  const float* aW1  = (const float*)d_in[3];
  const float* ab1  = (const float*)d_in[4];
  const float* aW2  = (const float*)d_in[5];
  const float* ab2  = (const float*)d_in[6];
  const float* dW1  = (const float*)d_in[7];
  const float* db1  = (const float*)d_in[8];
  const float* dW2  = (const float*)d_in[9];
  const float* db2  = (const float*)d_in[10];

  float* ws    = (float*)d_ws;
  float* UT    = ws + OFF_UT;
  float* B     = ws + OFF_B;
  float* L     = ws + OFF_L;
  float* pm    = ws + OFF_PM;
  float* part  = ws + OFF_PART;
  float* spart = ws + OFF_SPART;

  hipLaunchKernelGGL(k1_prep, dim3(2560), dim3(256), 0, stream,
                     qp, nf, npos, aW1, ab1, B, UT);
  hipLaunchKernelGGL(k2_logits, dim3(16, 32), dim3(256), 0, stream,
                     B, UT, aW2, ab2, qp, npos, L, pm);
  hipLaunchKernelGGL(k4_agg, dim3(512), dim3(256), 0, stream, L, pm, nf, part, spart);
  hipLaunchKernelGGL(k5_dec, dim3(2048), dim3(256), 0, stream,
                     part, spart, dW1, db1, dW2, db2, (float*)d_out);
}